// Round 3
// baseline (181.429 us; speedup 1.0000x reference)
//
#include <hip/hip_runtime.h>
#include <math.h>

#define CI   256
#define CO   256
#define HW   56
#define LQ   7
#define BETA 10.0f

typedef __attribute__((ext_vector_type(8))) short short8;
typedef __attribute__((ext_vector_type(4))) float f32x4;

__device__ __forceinline__ ushort f2bf(float f) {
    uint u = __float_as_uint(f);
    u += 0x7FFF + ((u >> 16) & 1);
    return (ushort)(u >> 16);
}

// ---------------- Kernel 1: soft-quantize weights -> packed bf16 ----------------
// W2 layout: [chunk 8][tap 9][kb 4][co 256][e 8] bf16  (k = chunk*32 + kb*8 + e)
__global__ void quant_weights(const float* __restrict__ p_c,
                              const float* __restrict__ q_level,
                              short* __restrict__ W2) {
    int idx = blockIdx.x * blockDim.x + threadIdx.x;  // (co, ci)
    if (idx >= CO * CI) return;
    int co = idx >> 8, ci = idx & 255;
    float ql[LQ];
#pragma unroll
    for (int l = 0; l < LQ; ++l) ql[l] = q_level[l];
    const float* p = p_c + (size_t)idx * 9 * LQ;
#pragma unroll
    for (int t = 0; t < 9; ++t) {
        float pv[LQ];
        float ss = 0.f;
#pragma unroll
        for (int l = 0; l < LQ; ++l) { pv[l] = p[t * LQ + l]; ss += pv[l] * pv[l]; }
        float inv = rsqrtf(ss) * BETA;
        float m = -1e30f;
#pragma unroll
        for (int l = 0; l < LQ; ++l) { pv[l] *= inv; m = fmaxf(m, pv[l]); }
        float den = 0.f, num = 0.f;
#pragma unroll
        for (int l = 0; l < LQ; ++l) {
            float e = expf(pv[l] - m);
            den += e;
            num += e * ql[l];
        }
        float val = num / den;
        int widx = ((((ci >> 5) * 9 + t) * 4 + ((ci >> 3) & 3)) * 2048) + co * 8 + (ci & 7);
        W2[widx] = (short)f2bf(val);
    }
}

// ---------------- Pre-pass A: zero the padded border of x_t ----------------
// x_t: [32][58][58][256] bf16, x_t[b][h+1][w+1][ci] = bf16(x[b][ci][h][w])
__global__ void prep_border(ushort* __restrict__ xt) {
    int idx = blockIdx.x * 256 + threadIdx.x;
    int b = blockIdx.y;
    if (idx >= 228 * 32) return;
    int pos = idx >> 5, chk = idx & 31;
    int hh, ww;
    if (pos < 58)       { hh = 0;  ww = pos; }
    else if (pos < 116) { hh = 57; ww = pos - 58; }
    else { int q = pos - 116; hh = 1 + (q >> 1); ww = (q & 1) ? 57 : 0; }
    size_t o = (((size_t)b * 58 + hh) * 58 + ww) * 256 + chk * 8;
    uint4 z = {0, 0, 0, 0};
    *(uint4*)&xt[o] = z;
}

// ---------------- Pre-pass B: interior transpose NCHW f32 -> NHWC bf16 ----------------
__global__ __launch_bounds__(256) void prep_main(const float* __restrict__ x,
                                                 ushort* __restrict__ xt) {
    __shared__ ushort ld[256 * 60];  // [ci][w], pitch 60 (b64-aligned writes)
    const int tid = threadIdx.x;
    const int h = blockIdx.x;   // 0..55
    const int b = blockIdx.y;
    const float* xp = x + ((size_t)b * CI) * 3136 + h * HW;
#pragma unroll
    for (int s = 0; s < 14; ++s) {
        int flat = s * 1024 + tid * 4;       // 256*56 = 14336 elems, 14 steps exact
        int ci = flat / 56;
        int w  = flat - ci * 56;
        const float4 v = *(const float4*)(xp + (size_t)ci * 3136 + w);
        ushort4 o;
        o.x = f2bf(v.x); o.y = f2bf(v.y); o.z = f2bf(v.z); o.w = f2bf(v.w);
        *(ushort4*)&ld[ci * 60 + w] = o;
    }
    __syncthreads();
    const int w = tid & 63;    // lanes w-contiguous -> conflict-free LDS reads
    const int wq = tid >> 6;   // wave id -> cig offset (4 waves fill each 64B sector)
    if (w < 56) {
        size_t obase = (((size_t)b * 58 + h + 1) * 58 + (w + 1)) * 256;
#pragma unroll
        for (int s = 0; s < 8; ++s) {
            int cig = s * 4 + wq;
            int base = (cig * 8) * 60 + w;
            uint u0 = (uint)ld[base]       | ((uint)ld[base + 60]  << 16);
            uint u1 = (uint)ld[base + 120] | ((uint)ld[base + 180] << 16);
            uint u2 = (uint)ld[base + 240] | ((uint)ld[base + 300] << 16);
            uint u3 = (uint)ld[base + 360] | ((uint)ld[base + 420] << 16);
            uint4 o = {u0, u1, u2, u3};
            *(uint4*)&xt[obase + cig * 8] = o;
        }
    }
}

// ---------------- Kernel 2 (fast): implicit-GEMM conv, glds + dbuf ----------------
// LDS tile per buffer: 1584 groups of 16B: group gg=(r*66+c)*4+kbq, content =
// x_t[b][h0+r][min(c,57)][ci0 + (kbq ^ ((c>>1)&3))*8 .. +8]. Linear LDS dest
// (glds requirement), swizzle applied on the global source address (m173).
__global__ __launch_bounds__(256, 2) void conv_mfma2(const ushort* __restrict__ xt_g,
                                                     const short* __restrict__ W2,
                                                     float* __restrict__ out) {
    __shared__ __align__(16) ushort xt[2][12672];  // 2 x 25344 B

    const int tid  = threadIdx.x;
    const int lane = tid & 63;
    const int wv   = tid >> 6;
    const int l15  = lane & 15;
    const int kb   = lane >> 4;
    const int wm    = (wv >> 1) * 64;
    const int wnrow = (wv & 1) * 2;

    const int h0  = blockIdx.x * 4;
    const int co0 = blockIdx.y * 128;
    const int b   = blockIdx.z;

    // per-thread staging source offsets (7 steps, uniform 7 glds per wave)
    int src_off[7];
#pragma unroll
    for (int s = 0; s < 7; ++s) {
        int gl = s * 64 + lane;
        int gg = wv * 396 + (gl < 396 ? gl : 0);
        int kbq = gg & 3, pos = gg >> 2;
        int r = pos / 66, c = pos - r * 66;
        int wp = c < 58 ? c : 57;
        int ci = (kbq ^ ((c >> 1) & 3)) << 3;
        src_off[s] = ((b * 58 + h0 + r) * 58 + wp) * 256 + ci;
    }

    f32x4 acc[4][8];
#pragma unroll
    for (int a = 0; a < 4; ++a)
#pragma unroll
        for (int f = 0; f < 8; ++f) acc[a][f] = (f32x4){0.f, 0.f, 0.f, 0.f};

    // prologue stage chunk 0 into buf 0
    {
        const ushort* sp = xt_g;
        ushort* lb = &xt[0][wv * 396 * 8];
#pragma unroll
        for (int s = 0; s < 7; ++s) {
            if (s * 64 + lane < 396)
                __builtin_amdgcn_global_load_lds(
                    (const __attribute__((address_space(1))) void*)(sp + src_off[s]),
                    (__attribute__((address_space(3))) void*)(lb + s * 512), 16, 0, 0);
        }
    }

    for (int ch = 0; ch < 8; ++ch) {
        if (ch < 7) {  // stage next chunk into other buffer (overlaps compute)
            const ushort* sp = xt_g + (ch + 1) * 32;
            ushort* lb = &xt[(ch + 1) & 1][wv * 396 * 8];
#pragma unroll
            for (int s = 0; s < 7; ++s) {
                if (s * 64 + lane < 396)
                    __builtin_amdgcn_global_load_lds(
                        (const __attribute__((address_space(1))) void*)(sp + src_off[s]),
                        (__attribute__((address_space(3))) void*)(lb + s * 512), 16, 0, 0);
            }
            asm volatile("s_waitcnt vmcnt(7)" ::: "memory");  // chunk ch landed
        } else {
            asm volatile("s_waitcnt vmcnt(0)" ::: "memory");
        }
        __builtin_amdgcn_s_barrier();

        const ushort* buf = xt[ch & 1];
#pragma unroll
        for (int kh = 0; kh < 3; ++kh) {
#pragma unroll
            for (int kw = 0; kw < 3; ++kw) {
                const int t = kh * 3 + kw;
                const short* ap = W2 + (size_t)(((ch * 9 + t) * 4 + kb) * 256 + co0 + wm + l15) * 8;
                short8 af[4];
#pragma unroll
                for (int a = 0; a < 4; ++a) af[a] = *(const short8*)(ap + a * 128);

                const int c0 = kw + l15;
                const int r0 = wnrow + kh;
                const ushort* bp = &buf[((r0 * 66 + c0) * 4 + (kb ^ ((c0 >> 1) & 3))) * 8];
                short8 bf[8];
#pragma unroll
                for (int f = 0; f < 8; ++f)
                    bf[f] = *(const short8*)(bp + (f >> 2) * 2112 + (f & 3) * 512);

#pragma unroll
                for (int a = 0; a < 4; ++a)
#pragma unroll
                    for (int f = 0; f < 8; ++f)
                        acc[a][f] = __builtin_amdgcn_mfma_f32_16x16x32_bf16(af[a], bf[f], acc[a][f], 0, 0, 0);
            }
        }
        asm volatile("s_waitcnt lgkmcnt(0)" ::: "memory");  // my LDS reads done
        __builtin_amdgcn_s_barrier();                       // all waves done reading
    }

#pragma unroll
    for (int a = 0; a < 4; ++a) {
#pragma unroll
        for (int f = 0; f < 8; ++f) {
            int wloc = (f & 3) * 16 + l15;
            if (wloc < HW) {
                int h = h0 + wnrow + (f >> 2);
#pragma unroll
                for (int j = 0; j < 4; ++j) {
                    int cog = co0 + wm + 16 * a + kb * 4 + j;
                    out[(((size_t)b * CO + cog) * HW + h) * HW + wloc] = acc[a][f][j];
                }
            }
        }
    }
}

// ---------------- Kernel 2 (fallback, round-2 verbatim): in-kernel cvt ----------------
__global__ __launch_bounds__(256, 2) void conv_mfma_fb(const float* __restrict__ x,
                                                       const short* __restrict__ W2,
                                                       float* __restrict__ out) {
    __shared__ __align__(16) short xs[6 * 72 * 32];

    const int tid  = threadIdx.x;
    const int lane = tid & 63;
    const int wv   = tid >> 6;
    const int l15  = lane & 15;
    const int kb   = lane >> 4;
    const int wm    = (wv >> 1) * 64;
    const int wnrow = (wv & 1) * 2;

    const int h0  = blockIdx.x * 4;
    const int co0 = blockIdx.y * 128;
    const int b   = blockIdx.z;

    f32x4 acc[4][8];
#pragma unroll
    for (int a = 0; a < 4; ++a)
#pragma unroll
        for (int f = 0; f < 8; ++f) acc[a][f] = (f32x4){0.f, 0.f, 0.f, 0.f};

    const float* xb = x + (size_t)b * CI * HW * HW;

    for (int ch = 0; ch < 8; ++ch) {
        const int ci0 = ch * 32;
        for (int f = tid; f < 6 * 66; f += 256) {
            int r = f / 66, c = f % 66;
            int h = h0 - 1 + r, wc = c - 1;
            bool valid = (h >= 0) & (h < HW) & (wc >= 0) & (wc < HW);
            const float* xsrc = xb + (size_t)ci0 * 3136 + (valid ? (h * HW + wc) : 0);
            int sw = (c >> 1) & 3;
            int sbase = (r * 72 + c) * 32;
#pragma unroll
            for (int k = 0; k < 4; ++k) {
                short8 pk;
#pragma unroll
                for (int e = 0; e < 8; ++e) {
                    float v = xsrc[(size_t)(k * 8 + e) * 3136];
                    pk[e] = (short)f2bf(valid ? v : 0.f);
                }
                *(short8*)&xs[sbase + ((k ^ sw) * 8)] = pk;
            }
        }
        __syncthreads();

#pragma unroll
        for (int kh = 0; kh < 3; ++kh) {
#pragma unroll
            for (int kw = 0; kw < 3; ++kw) {
                const int t = kh * 3 + kw;
                const short* ap = W2 + (size_t)((((ch * 9 + t) * 4 + kb) * 256) + co0 + wm + l15) * 8;
                short8 af[4];
#pragma unroll
                for (int a = 0; a < 4; ++a) af[a] = *(const short8*)(ap + a * 128);

                const int c0 = kw + l15;
                const int r0 = wnrow + kh;
                const short* bp = &xs[(r0 * 72 + c0) * 32 + ((kb ^ ((c0 >> 1) & 3)) * 8)];
                short8 bf[8];
#pragma unroll
                for (int f = 0; f < 8; ++f)
                    bf[f] = *(const short8*)(bp + (f >> 2) * 2304 + (f & 3) * 512);

#pragma unroll
                for (int a = 0; a < 4; ++a)
#pragma unroll
                    for (int f = 0; f < 8; ++f)
                        acc[a][f] = __builtin_amdgcn_mfma_f32_16x16x32_bf16(af[a], bf[f], acc[a][f], 0, 0, 0);
            }
        }
        __syncthreads();
    }

#pragma unroll
    for (int a = 0; a < 4; ++a) {
#pragma unroll
        for (int f = 0; f < 8; ++f) {
            int wloc = (f & 3) * 16 + l15;
            if (wloc < HW) {
                int h = h0 + wnrow + (f >> 2);
#pragma unroll
                for (int j = 0; j < 4; ++j) {
                    int cog = co0 + wm + 16 * a + kb * 4 + j;
                    out[(((size_t)b * CO + cog) * HW + h) * HW + wloc] = acc[a][f][j];
                }
            }
        }
    }
}

extern "C" void kernel_launch(void* const* d_in, const int* in_sizes, int n_in,
                              void* d_out, int out_size, void* d_ws, size_t ws_size,
                              hipStream_t stream) {
    const float* x       = (const float*)d_in[0]; // (32,256,56,56)
    const float* p_c     = (const float*)d_in[1]; // (256,256,3,3,7)
    const float* q_level = (const float*)d_in[2]; // (7,)
    float* out = (float*)d_out;

    short* W2 = (short*)d_ws;                          // 1.18 MB at offset 0
    const size_t XT_OFF = 2u * 1024 * 1024;
    const size_t need = XT_OFF + (size_t)32 * 3364 * 256 * 2;  // + 55.1 MB NHWC bf16

    quant_weights<<<(CO * CI + 255) / 256, 256, 0, stream>>>(p_c, q_level, W2);

    if (ws_size >= need) {
        ushort* xt_g = (ushort*)((char*)d_ws + XT_OFF);
        prep_border<<<dim3(29, 32), 256, 0, stream>>>(xt_g);
        prep_main<<<dim3(56, 32), 256, 0, stream>>>(x, xt_g);
        conv_mfma2<<<dim3(14, 2, 32), 256, 0, stream>>>(xt_g, W2, out);
    } else {
        conv_mfma_fb<<<dim3(14, 2, 32), 256, 0, stream>>>(x, W2, out);
    }
}